// Round 16
// baseline (263.795 us; speedup 1.0000x reference)
//
#include <hip/hip_runtime.h>
#include <hip/hip_fp16.h>

#define NN 50000
#define EE 800000
#define DD 64
#define GG 512
#define HIDD 64
#define D2 128
#define NBLK 196          // ceil(NN/256)

__device__ inline __half2 mk2(float a, float b) {
    __half2 h; h.x = __float2half_rn(a); h.y = __float2half_rn(b); return h;
}

// ---------------- zero cnt_in ----------------
__global__ void k_zero(int* __restrict__ cnt_in) {
    int i = blockIdx.x * blockDim.x + threadIdx.x;
    if (i < NN) cnt_in[i] = 0;
}

// ------ count + rank: one atomic pass; rank stored coalesced ------
__global__ void k_count_rank(const int* __restrict__ dst, int* __restrict__ cnt_in,
                             int* __restrict__ rank) {
    int e = blockIdx.x * blockDim.x + threadIdx.x;
    if (e < EE) rank[e] = atomicAdd(&cnt_in[dst[e]], 1);
}

// ---- fused scan: rowptr = exclusive_scan(cnt_in)  (one kernel, 196 blocks) --
// each block sums all of cnt_in before its chunk (L2-resident, ~cheap), then
// block-local scan; writes rowptr[i], rowptr[NN] = EE.
__global__ __launch_bounds__(256) void k_scan_rowptr(const int* __restrict__ cnt_in,
                                                     int* __restrict__ rowptr) {
    int b = blockIdx.x, t = threadIdx.x;
    int base = b * 256;
    // sum of all elements before this block's chunk
    int prior = 0;
    for (int i = t; i < base; i += 256) prior += cnt_in[i];
    __shared__ int red[256];
    red[t] = prior;
    __syncthreads();
    for (int off = 128; off > 0; off >>= 1) {
        if (t < off) red[t] += red[t + off];
        __syncthreads();
    }
    int blockPrefix = red[0];
    __syncthreads();
    // local inclusive scan of this chunk
    int i = base + t;
    int v = (i < NN) ? cnt_in[i] : 0;
    __shared__ int s[256];
    s[t] = v;
    __syncthreads();
    for (int off = 1; off < 256; off <<= 1) {
        int add = (t >= off) ? s[t - off] : 0;
        __syncthreads();
        s[t] += add;
        __syncthreads();
    }
    if (i <= NN) rowptr[i] = s[t] - v + blockPrefix;   // exclusive
}

// ------ place: csr[rowptr[dst]+rank] = src; no atomics, fire-and-forget ------
__global__ void k_place(const int* __restrict__ src, const int* __restrict__ dst,
                        const int* __restrict__ rank, const int* __restrict__ rowptr,
                        int* __restrict__ csr) {
    int e = blockIdx.x * blockDim.x + threadIdx.x;
    if (e < EE)
        csr[rowptr[dst[e]] + rank[e]] = src[e];
}

// -- GEMM1 (reg-tiled): t1h = half2((x@W1)*dinv); tile 128r x 64c --
__global__ __launch_bounds__(256) void k_gemm1(const float* __restrict__ x,
        const float* __restrict__ W1, const int* __restrict__ cnt_in,
        __half2* __restrict__ t1h) {
    __shared__ float As[128][68];   // x-tile row-major [r][k], pad 64->68
    __shared__ float Bs[DD][DD];    // W1 [k][c]
    int t = threadIdx.x;
    int row0 = blockIdx.x * 128;
    #pragma unroll
    for (int j = 0; j < 4; ++j) {               // W1: 1024 float4
        int id = t + j * 256;
        int k = id >> 4, c4 = (id & 15) * 4;
        *(float4*)&Bs[k][c4] = *(const float4*)&W1[k * DD + c4];
    }
    #pragma unroll
    for (int j = 0; j < 8; ++j) {               // x-tile: 2048 float4
        int id = t + j * 256;
        int r = id >> 4, k4 = (id & 15) * 4;
        int gr = row0 + r;
        float4 v = make_float4(0.f, 0.f, 0.f, 0.f);
        if (gr < NN) v = *(const float4*)&x[gr * DD + k4];
        *(float4*)&As[r][k4] = v;
    }
    __syncthreads();
    int rbase = (t >> 3) * 4, cbase = (t & 7) * 8;
    float4 cL0 = make_float4(0.f,0.f,0.f,0.f), cH0 = cL0;
    float4 cL1 = cL0, cH1 = cL0, cL2 = cL0, cH2 = cL0, cL3 = cL0, cH3 = cL0;
    #pragma unroll 2
    for (int k = 0; k < DD; ++k) {
        float4 bL = *(const float4*)&Bs[k][cbase];
        float4 bH = *(const float4*)&Bs[k][cbase + 4];
        float a0 = As[rbase + 0][k];
        float a1 = As[rbase + 1][k];
        float a2 = As[rbase + 2][k];
        float a3 = As[rbase + 3][k];
        cL0 += bL * a0;  cH0 += bH * a0;
        cL1 += bL * a1;  cH1 += bH * a1;
        cL2 += bL * a2;  cH2 += bH * a2;
        cL3 += bL * a3;  cH3 += bH * a3;
    }
    int h2base = (t & 7) * 4;       // half2 index within row (32 half2/row)
    int gr0 = row0 + rbase;
    #define STORE_T1(idx, CL, CH) \
        if (gr0 + idx < NN) { \
            float d = rsqrtf((float)cnt_in[gr0 + idx] + 1.0f); \
            __half2 p0 = mk2(CL.x * d, CL.y * d), p1 = mk2(CL.z * d, CL.w * d); \
            __half2 p2 = mk2(CH.x * d, CH.y * d), p3 = mk2(CH.z * d, CH.w * d); \
            uint4 pk; pk.x = *(unsigned*)&p0; pk.y = *(unsigned*)&p1; \
            pk.z = *(unsigned*)&p2; pk.w = *(unsigned*)&p3; \
            *(uint4*)(t1h + (size_t)(gr0 + idx) * 32 + h2base) = pk; }
    STORE_T1(0, cL0, cH0)
    STORE_T1(1, cL1, cH1)
    STORE_T1(2, cL2, cH2)
    STORE_T1(3, cL3, cH3)
    #undef STORE_T1
}

// -- agg1 (half2 gather, half-wave per node): u = half2(dinv*relu(dinv*S + b1)) --
__global__ __launch_bounds__(256) void k_agg1(const int* __restrict__ rowptr,
        const int* __restrict__ csr, const __half2* __restrict__ t1h,
        const int* __restrict__ cnt_in, const float* __restrict__ b1,
        __half2* __restrict__ u_h) {
    int gid = blockIdx.x * blockDim.x + threadIdx.x;
    int node = gid >> 5;
    int p = threadIdx.x & 31;           // channel pair
    if (node >= NN) return;
    int beg = rowptr[node], end = rowptr[node + 1];
    float2 A0 = __half22float2(t1h[(size_t)node * 32 + p]);   // self-loop
    float2 A1 = make_float2(0.f, 0.f), A2 = A1, A3 = A1;
    int e = beg;
    for (; e + 4 <= end; e += 4) {
        int s0 = csr[e], s1 = csr[e + 1], s2 = csr[e + 2], s3 = csr[e + 3];
        float2 v0 = __half22float2(t1h[(size_t)s0 * 32 + p]);
        float2 v1 = __half22float2(t1h[(size_t)s1 * 32 + p]);
        float2 v2 = __half22float2(t1h[(size_t)s2 * 32 + p]);
        float2 v3 = __half22float2(t1h[(size_t)s3 * 32 + p]);
        A0.x += v0.x; A0.y += v0.y;
        A1.x += v1.x; A1.y += v1.y;
        A2.x += v2.x; A2.y += v2.y;
        A3.x += v3.x; A3.y += v3.y;
    }
    for (; e < end; ++e) {
        float2 v = __half22float2(t1h[(size_t)csr[e] * 32 + p]);
        A0.x += v.x; A0.y += v.y;
    }
    float sx = (A0.x + A1.x) + (A2.x + A3.x);
    float sy = (A0.y + A1.y) + (A2.y + A3.y);
    float d = rsqrtf((float)cnt_in[node] + 1.0f);
    float2 bb = ((const float2*)b1)[p];
    float h0 = fmaxf(d * sx + bb.x, 0.0f);
    float h1 = fmaxf(d * sy + bb.y, 0.0f);
    u_h[(size_t)node * 32 + p] = mk2(d * h0, d * h1);
}

// -- pool3: fused {agg2 gather + per-graph mean + W2/Wfc chain} --
// block g: nodes [beg,end) (batch sorted). 8 subwarps x 32 lanes; lane p owns
// channel pair p; subwarp sw processes nodes beg+sw, beg+sw+8, ...
// out[g] = ((mean_i dinv_i*(u_i + sum_src u_src)) @ W2 + b2) @ Wfc + bfc
__global__ __launch_bounds__(256) void k_pool3(const int* __restrict__ rowptr,
        const int* __restrict__ csr, const __half2* __restrict__ u_h,
        const int* __restrict__ cnt_in, const int* __restrict__ batch,
        const float* __restrict__ W2, const float* __restrict__ b2,
        const float* __restrict__ Wfc, const float* __restrict__ bfc,
        float* __restrict__ out) {
    int g = blockIdx.x;
    int t = threadIdx.x;
    int sw = t >> 5, p = t & 31;
    // segment [beg,end) of sorted batch
    int lo = 0, hi = NN;
    while (lo < hi) { int mid = (lo + hi) >> 1; if (batch[mid] < g) lo = mid + 1; else hi = mid; }
    int beg = lo;
    hi = NN;
    while (lo < hi) { int mid = (lo + hi) >> 1; if (batch[mid] < g + 1) lo = mid + 1; else hi = mid; }
    int end = lo;
    int n = end - beg;

    float2 gacc = make_float2(0.f, 0.f);
    for (int node = beg + sw; node < end; node += 8) {
        int nb = rowptr[node], ne = rowptr[node + 1];
        float2 A0 = __half22float2(u_h[(size_t)node * 32 + p]);   // self-loop
        float2 A1 = make_float2(0.f, 0.f), A2 = A1, A3 = A1;
        int e = nb;
        for (; e + 4 <= ne; e += 4) {
            int s0 = csr[e], s1 = csr[e + 1], s2 = csr[e + 2], s3 = csr[e + 3];
            float2 v0 = __half22float2(u_h[(size_t)s0 * 32 + p]);
            float2 v1 = __half22float2(u_h[(size_t)s1 * 32 + p]);
            float2 v2 = __half22float2(u_h[(size_t)s2 * 32 + p]);
            float2 v3 = __half22float2(u_h[(size_t)s3 * 32 + p]);
            A0.x += v0.x; A0.y += v0.y;
            A1.x += v1.x; A1.y += v1.y;
            A2.x += v2.x; A2.y += v2.y;
            A3.x += v3.x; A3.y += v3.y;
        }
        for (; e < ne; ++e) {
            float2 v = __half22float2(u_h[(size_t)csr[e] * 32 + p]);
            A0.x += v.x; A0.y += v.y;
        }
        float d = rsqrtf((float)cnt_in[node] + 1.0f);
        gacc.x += d * ((A0.x + A1.x) + (A2.x + A3.x));
        gacc.y += d * ((A0.y + A1.y) + (A2.y + A3.y));
    }
    __shared__ float2 red[32][9];       // [pair][subwarp], pad 8->9
    red[p][sw] = gacc;
    __syncthreads();
    __shared__ float pm[DD];
    if (t < 32) {
        float2 s = red[t][0];
        #pragma unroll
        for (int j = 1; j < 8; ++j) { s.x += red[t][j].x; s.y += red[t][j].y; }
        float scale = (n > 0) ? (1.0f / (float)n) : 0.0f;
        pm[2 * t]     = s.x * scale;
        pm[2 * t + 1] = s.y * scale;
    }
    __syncthreads();
    __shared__ float tt[D2];
    if (t < D2) {
        float acc = (n > 0) ? b2[t] : 0.0f;
        #pragma unroll 4
        for (int k = 0; k < DD; ++k)
            acc += pm[k] * W2[k * D2 + t];
        tt[t] = acc;
    }
    __syncthreads();
    if (t < HIDD) {
        float o = bfc[t];
        #pragma unroll 4
        for (int k = 0; k < D2; ++k)
            o += tt[k] * Wfc[k * HIDD + t];
        out[g * HIDD + t] = o;
    }
}

extern "C" void kernel_launch(void* const* d_in, const int* in_sizes, int n_in,
                              void* d_out, int out_size, void* d_ws, size_t ws_size,
                              hipStream_t stream) {
    const float* x     = (const float*)d_in[0];
    const int*   ei    = (const int*)  d_in[1];
    const int*   batch = (const int*)  d_in[2];
    const float* W1    = (const float*)d_in[3];
    const float* b1    = (const float*)d_in[4];
    const float* W2    = (const float*)d_in[5];
    const float* b2    = (const float*)d_in[6];
    const float* Wfc   = (const float*)d_in[7];
    const float* bfc   = (const float*)d_in[8];
    float* out = (float*)d_out;

    const int* src = ei;
    const int* dst = ei + EE;

    // ---- workspace layout ----
    // [t1h 6.4MB][u_h 6.4MB][ints]
    char* base = (char*)d_ws;
    __half2* t1h = (__half2*)base;                       // NN*32 half2
    __half2* u_h = (__half2*)(base + (size_t)NN * 128);  // NN*32 half2
    int* iws    = (int*)(base + (size_t)NN * 256);
    int* cnt_in = iws;                          // NN (pad 50048)
    int* rowptr = cnt_in + 50048;               // NN+1 (pad 50304)
    int* rank   = rowptr + 50304;               // EE
    int* csr    = rank + EE;                    // EE
    // total ≈ 19.5 MB

    k_zero       <<<NBLK, 256, 0, stream>>>(cnt_in);
    k_count_rank <<<(EE + 255) / 256, 256, 0, stream>>>(dst, cnt_in, rank);
    k_scan_rowptr<<<NBLK, 256, 0, stream>>>(cnt_in, rowptr);
    k_place      <<<(EE + 255) / 256, 256, 0, stream>>>(src, dst, rank, rowptr, csr);
    k_gemm1      <<<(NN + 127) / 128, 256, 0, stream>>>(x, W1, cnt_in, t1h);
    k_agg1       <<<(NN * 32 + 255) / 256, 256, 0, stream>>>(rowptr, csr, t1h, cnt_in, b1, u_h);
    k_pool3      <<<GG, 256, 0, stream>>>(rowptr, csr, u_h, cnt_in, batch, W2, b2, Wfc, bfc, out);
}